// Round 19
// baseline (129.935 us; speedup 1.0000x reference)
//
#include <hip/hip_runtime.h>
#include <hip/hip_bf16.h>
#include <math.h>

#define NEG_SLOPE 0.01f

// Shapes tuned for: N=65536 nodes, E=1048576 edges, dim 64.
// Assumptions: N <= 2^16 (src packs into 16 bits of the edge word).
// r19 = r18 (best: 121.7us) with node_pre occupancy doubled:
//   - prep_al (1 block) computes al/ar once; node_pre loads avecs from global
//     (preamble was re-run by all 1024 blocks for one tile each)
//   - 512-thread blocks, wave owns 8 nodes -> 8192 waves = 32/CU (100%)
// main_k is at its structural fetch floor (130MB = 8 XCD x table) -- unchanged.

__device__ __forceinline__ unsigned int pack2bf16(float pz, float g)
{
    __hip_bfloat16 a = __float2bfloat16(pz);   // RNE
    __hip_bfloat16 b = __float2bfloat16(g);
    unsigned short ua = *(unsigned short*)&a;
    unsigned short ub = *(unsigned short*)&b;
    return ((unsigned int)ub << 16) | ua;
}

__device__ __forceinline__ unsigned short f2bf(float x)
{
    __hip_bfloat16 b = __float2bfloat16(x);
    return *(unsigned short*)&b;
}

__device__ __forceinline__ int rdlane_i(int x, int l)
{
    return __builtin_amdgcn_readlane(x, l);
}
__device__ __forceinline__ float rdlane_f(float x, int l)
{
    return __int_as_float(__builtin_amdgcn_readlane(__float_as_int(x), l));
}
__device__ __forceinline__ float lo16(unsigned int u) { return __uint_as_float(u << 16); }
__device__ __forceinline__ float hi16(unsigned int u) { return __uint_as_float(u & 0xffff0000u); }

// ---------------------------------------------------------------------------
// prep_al: one block; alar[0:64] = attl@Wa, alar[64:128] = attr@Wa.
// ---------------------------------------------------------------------------
__global__ __launch_bounds__(256) void prep_al(
    const float* __restrict__ Wa,
    const float* __restrict__ attl, const float* __restrict__ attr,
    float* __restrict__ alar)
{
    __shared__ float pal[4][64], par[4][64];
    int t = threadIdx.x, lane = t & 63, w = t >> 6;
    float ald = 0.f, ard = 0.f;
    #pragma unroll
    for (int kk = 0; kk < 16; ++kk) {
        int k = w * 16 + kk;
        float wa = Wa[k * 64 + lane];
        ald = fmaf(attl[k], wa, ald);
        ard = fmaf(attr[k], wa, ard);
    }
    pal[w][lane] = ald;
    par[w][lane] = ard;
    __syncthreads();
    if (w == 0) {
        alar[lane]      = pal[0][lane] + pal[1][lane] + pal[2][lane] + pal[3][lane];
        alar[64 + lane] = par[0][lane] + par[1][lane] + par[2][lane] + par[3][lane];
    }
}

// ---------------------------------------------------------------------------
// node_pre: 512 threads (8 waves), wave owns 8 nodes. Tile-loop body keeps
// the r9 dataflow (LDS vtile stride-68, avecs in LDS, K-chunked gp).
//   slvr[n] = (v[n].al, v[n].gr)   srvg[n] = (v[n].ar, v[n].gl)
//   pzgp[n][d] = pack(bf16(proj_z[n][d]), bf16((Wg @ v[n])[d]))
// ---------------------------------------------------------------------------
__global__ __launch_bounds__(512) void node_pre(
    const float* __restrict__ v, const float* __restrict__ proj_z,
    const float* __restrict__ alar,
    const float* __restrict__ Wg, const float* __restrict__ gl,
    const float* __restrict__ gr,
    float2* __restrict__ slvr, float2* __restrict__ srvg,
    unsigned int* __restrict__ pzgp, int N)
{
    __shared__ float vtile[64 * 68];     // stride 68: conflict-free
    __shared__ float avecs[4][64];       // 0=al, 1=ar, 2=gl, 3=gr

    int t = threadIdx.x;
    int lane = t & 63;
    int w = t >> 6;                      // 0..7

    // fast preamble: avecs from global (one coalesced burst)
    if (t < 256) {
        int row = t >> 6, col = t & 63;
        float val;
        if (row == 0)      val = alar[col];
        else if (row == 1) val = alar[64 + col];
        else if (row == 2) val = gl[col];
        else               val = gr[col];
        avecs[row][col] = val;
    }

    for (int tile = blockIdx.x; (size_t)tile * 64 < (size_t)N; tile += gridDim.x) {
        int base = tile * 64;
        __syncthreads();                 // protects vtile AND first-use of avecs

        // stage 64x64 tile: thread t owns node t>>3, cols (t&7)*8..+7.
        // Fused scalar partial dots on the in-register values.
        float p1 = 0.f, p2 = 0.f, p3 = 0.f, p4 = 0.f;
        #pragma unroll
        for (int i = 0; i < 2; ++i) {
            int el = t * 8 + i * 4;                     // 0..4095
            size_t gidx = (size_t)base * 64 + el;
            int c = (t & 7) * 8 + i * 4;                // col within row
            if (gidx + 3 < (size_t)N * 64) {
                float4 q = *(const float4*)(v + gidx);
                int r = el >> 6;
                *(float4*)&vtile[r * 68 + c] = q;
                float4 a0 = *(const float4*)&avecs[0][c];
                float4 a1 = *(const float4*)&avecs[1][c];
                float4 a2 = *(const float4*)&avecs[2][c];
                float4 a3 = *(const float4*)&avecs[3][c];
                p1 = fmaf(a0.x, q.x, fmaf(a0.y, q.y, fmaf(a0.z, q.z, fmaf(a0.w, q.w, p1))));
                p2 = fmaf(a1.x, q.x, fmaf(a1.y, q.y, fmaf(a1.z, q.z, fmaf(a1.w, q.w, p2))));
                p3 = fmaf(a2.x, q.x, fmaf(a2.y, q.y, fmaf(a2.z, q.z, fmaf(a2.w, q.w, p3))));
                p4 = fmaf(a3.x, q.x, fmaf(a3.y, q.y, fmaf(a3.z, q.z, fmaf(a3.w, q.w, p4))));
            }
        }
        __syncthreads();

        // 8-thread reduce (threads 8r..8r+7 share node r)
        p1 += __shfl_xor(p1, 1); p1 += __shfl_xor(p1, 2); p1 += __shfl_xor(p1, 4);
        p2 += __shfl_xor(p2, 1); p2 += __shfl_xor(p2, 2); p2 += __shfl_xor(p2, 4);
        p3 += __shfl_xor(p3, 1); p3 += __shfl_xor(p3, 2); p3 += __shfl_xor(p3, 4);
        p4 += __shfl_xor(p4, 1); p4 += __shfl_xor(p4, 2); p4 += __shfl_xor(p4, 4);
        if ((t & 7) == 0) {
            int node = base + (t >> 3);
            if (node < N) {
                slvr[node] = make_float2(p1, p4);   // (sl, vr)
                srvg[node] = make_float2(p2, p3);   // (sr, vg0)
            }
        }

        // gp = vtile @ Wg^T, K-chunked; wave w owns nodes w*8..w*8+7
        float accs[8];
        #pragma unroll
        for (int n = 0; n < 8; ++n) accs[n] = 0.f;

        #pragma unroll 1
        for (int kc = 0; kc < 4; ++kc) {
            const float* wrow = Wg + lane * 64 + kc * 16;
            float4 w0 = *(const float4*)(wrow + 0);
            float4 w1 = *(const float4*)(wrow + 4);
            float4 w2 = *(const float4*)(wrow + 8);
            float4 w3 = *(const float4*)(wrow + 12);
            #pragma unroll
            for (int n = 0; n < 8; ++n) {
                const float* vp = &vtile[(w * 8 + n) * 68 + kc * 16];
                float4 q0 = *(const float4*)(vp + 0);
                float4 q1 = *(const float4*)(vp + 4);
                float4 q2 = *(const float4*)(vp + 8);
                float4 q3 = *(const float4*)(vp + 12);
                float a = accs[n];
                a = fmaf(w0.x, q0.x, a); a = fmaf(w0.y, q0.y, a);
                a = fmaf(w0.z, q0.z, a); a = fmaf(w0.w, q0.w, a);
                a = fmaf(w1.x, q1.x, a); a = fmaf(w1.y, q1.y, a);
                a = fmaf(w1.z, q1.z, a); a = fmaf(w1.w, q1.w, a);
                a = fmaf(w2.x, q2.x, a); a = fmaf(w2.y, q2.y, a);
                a = fmaf(w2.z, q2.z, a); a = fmaf(w2.w, q2.w, a);
                a = fmaf(w3.x, q3.x, a); a = fmaf(w3.y, q3.y, a);
                a = fmaf(w3.z, q3.z, a); a = fmaf(w3.w, q3.w, a);
                accs[n] = a;
            }
        }

        #pragma unroll
        for (int n = 0; n < 8; ++n) {
            int node = base + w * 8 + n;
            if (node < N) {
                float pz = proj_z[(size_t)node * 64 + lane];
                pzgp[(size_t)node * 64 + lane] = pack2bf16(pz, accs[n]);
            }
        }
    }
}

// ---------------------------------------------------------------------------
// Bucket-sort CSR build (r18 verbatim; LDS atomics only).
// ---------------------------------------------------------------------------
__global__ __launch_bounds__(256) void k_hist(const int* __restrict__ dst,
                                              int* __restrict__ cnt,
                                              int E, int NB, int NBUCK)
{
    __shared__ int h[256];
    int t = threadIdx.x, b = blockIdx.x;
    h[t] = 0;
    __syncthreads();
    int base = b * 4096;
    for (int i = t; i < 4096; i += 256) {
        int e = base + i;
        if (e < E) atomicAdd(&h[dst[e] >> 8], 1);
    }
    __syncthreads();
    for (int q = t; q < NBUCK; q += 256) cnt[q * NB + b] = h[q];
}

__global__ __launch_bounds__(256) void ps_block(int* __restrict__ data,
                                                int* __restrict__ bsum, int M)
{
    __shared__ int tmp[256];
    int t = threadIdx.x;
    int i = blockIdx.x * 256 + t;
    int val = (i < M) ? data[i] : 0;
    tmp[t] = val;
    __syncthreads();
    #pragma unroll
    for (int o = 1; o < 256; o <<= 1) {
        int x = (t >= o) ? tmp[t - o] : 0;
        __syncthreads();
        tmp[t] += x;
        __syncthreads();
    }
    if (i < M) data[i] = tmp[t] - val;
    if (t == 255) bsum[blockIdx.x] = tmp[255];
}

__global__ __launch_bounds__(256) void ps_top(int* __restrict__ bsum, int NBLK)
{
    __shared__ int tmp[256];
    int t = threadIdx.x;
    int val = (t < NBLK) ? bsum[t] : 0;
    tmp[t] = val;
    __syncthreads();
    #pragma unroll
    for (int o = 1; o < 256; o <<= 1) {
        int x = (t >= o) ? tmp[t - o] : 0;
        __syncthreads();
        tmp[t] += x;
        __syncthreads();
    }
    if (t < NBLK) bsum[t] = tmp[t] - val;
}

__global__ __launch_bounds__(256) void k_scat1(
    const int* __restrict__ dst, const int* __restrict__ src,
    const float* __restrict__ pre_w, const int* __restrict__ pos,
    const int* __restrict__ bsum,
    int2* __restrict__ buf1, int E, int NB, int NBUCK)
{
    __shared__ int cur[256];
    int t = threadIdx.x, b = blockIdx.x;
    for (int q = t; q < NBUCK; q += 256) {
        int idx = q * NB + b;
        cur[q] = pos[idx] + bsum[idx >> 8];
    }
    __syncthreads();
    int base = b * 4096;
    for (int i = t; i < 4096; i += 256) {
        int e = base + i;
        if (e < E) {
            int d = dst[e];
            int p = atomicAdd(&cur[d >> 8], 1);    // LDS atomic
            int2 pk;
            pk.x = ((d & 255) << 24) | src[e];
            pk.y = __float_as_int(pre_w[e]);
            buf1[p] = pk;
        }
    }
}

// scat2 emits 4-byte packed edges: src:16 | pw(bf16):16
__global__ __launch_bounds__(256) void k_scat2(
    const int2* __restrict__ buf1, const int* __restrict__ pos,
    const int* __restrict__ bsum,
    unsigned int* __restrict__ edata, int* __restrict__ deg,
    int* __restrict__ offs,
    int E, int NB, int NBUCK, int N)
{
    __shared__ int h[256], bs[256];
    int B = blockIdx.x, t = threadIdx.x;
    int i0 = B * NB;
    int lo = pos[i0] + bsum[i0 >> 8];
    int hi = E;
    if (B + 1 < NBUCK) {
        int i1 = (B + 1) * NB;
        hi = pos[i1] + bsum[i1 >> 8];
    }
    int cB = hi - lo;

    h[t] = 0;
    __syncthreads();
    for (int i = t; i < cB; i += 256)
        atomicAdd(&h[(unsigned)buf1[lo + i].x >> 24], 1);
    __syncthreads();

    int val = h[t];
    bs[t] = val;
    __syncthreads();
    #pragma unroll
    for (int o = 1; o < 256; o <<= 1) {
        int x = (t >= o) ? bs[t - o] : 0;
        __syncthreads();
        bs[t] += x;
        __syncthreads();
    }
    int mybs = bs[t] - val;

    int node = (B << 8) + t;
    if (node < N) { deg[node] = val; offs[node] = lo + mybs; }

    h[t] = mybs;
    __syncthreads();
    for (int i = t; i < cB; i += 256) {
        int2 pk = buf1[lo + i];
        int bin = (unsigned)pk.x >> 24;
        int p = atomicAdd(&h[bin], 1);    // LDS atomic
        unsigned int srcw = (unsigned)pk.x & 0x0000FFFFu;           // src (16b)
        unsigned int pwb  = (unsigned int)f2bf(__int_as_float(pk.y));
        edata[lo + p] = srcw | (pwb << 16);
    }
}

// ---------------------------------------------------------------------------
// main_k: r18 verbatim (one wave per dst node, 2-wave blocks, 8-wide gather,
// no-max softmax, 4-byte packed edges).
// ---------------------------------------------------------------------------
__global__ __launch_bounds__(128) void main_k(
    const float* __restrict__ proj_z,
    const float2* __restrict__ slvr, const float2* __restrict__ srvg,
    const unsigned int* __restrict__ pzgp, const float* __restrict__ gm,
    const int* __restrict__ deg, const int* __restrict__ offs,
    const unsigned int* __restrict__ edata,
    float* __restrict__ out, int N)
{
    int n = (blockIdx.x * 128 + threadIdx.x) >> 6;
    int lane = threadIdx.x & 63;
    if (n >= N) return;

    int dg = deg[n];
    int st = offs[n];
    float2 sv = srvg[n];
    float srn = sv.x, vg0n = sv.y;

    float den = 0.f, hacc = 0.f, mf = -INFINITY, msum = 0.f;

    for (int base = 0; base < dg; base += 64) {
        int cnt = min(64, dg - base);

        int s_e = 0; float pw = 0.f, ex = 0.f, vre = 0.f;
        if (lane < cnt) {
            unsigned int ed = edata[st + base + lane];
            s_e = (int)(ed & 0xFFFFu);
            pw  = __uint_as_float(ed & 0xFFFF0000u);   // bf16 -> f32 (hi bits)
            float2 f = slvr[s_e];
            float a = fmaf(pw, f.x, srn);
            float lr = (a >= 0.f) ? a : NEG_SLOPE * a;
            ex = __expf(lr);                 // no max subtraction (bounded logits)
            vre = f.y;
        }

        // lane-parallel reductions for den and msum
        float rs1 = ex, rs2 = pw * vre;
        #pragma unroll
        for (int o = 32; o > 0; o >>= 1) {
            rs1 += __shfl_xor(rs1, o);
            rs2 += __shfl_xor(rs2, o);
        }
        den += rs1; msum += rs2;

        // per-dim gathers: readlane broadcasts + 8 loads in flight
        int j = 0;
        for (; j + 7 < cnt; j += 8) {
            int s0 = rdlane_i(s_e, j + 0), s1 = rdlane_i(s_e, j + 1);
            int s2 = rdlane_i(s_e, j + 2), s3 = rdlane_i(s_e, j + 3);
            int s4 = rdlane_i(s_e, j + 4), s5 = rdlane_i(s_e, j + 5);
            int s6 = rdlane_i(s_e, j + 6), s7 = rdlane_i(s_e, j + 7);
            unsigned int u0 = pzgp[(size_t)s0 * 64 + lane];
            unsigned int u1 = pzgp[(size_t)s1 * 64 + lane];
            unsigned int u2 = pzgp[(size_t)s2 * 64 + lane];
            unsigned int u3 = pzgp[(size_t)s3 * 64 + lane];
            unsigned int u4 = pzgp[(size_t)s4 * 64 + lane];
            unsigned int u5 = pzgp[(size_t)s5 * 64 + lane];
            unsigned int u6 = pzgp[(size_t)s6 * 64 + lane];
            unsigned int u7 = pzgp[(size_t)s7 * 64 + lane];
            float e0 = rdlane_f(ex, j + 0), e1 = rdlane_f(ex, j + 1);
            float e2 = rdlane_f(ex, j + 2), e3 = rdlane_f(ex, j + 3);
            float e4 = rdlane_f(ex, j + 4), e5 = rdlane_f(ex, j + 5);
            float e6 = rdlane_f(ex, j + 6), e7 = rdlane_f(ex, j + 7);
            float q0 = rdlane_f(pw, j + 0), q1 = rdlane_f(pw, j + 1);
            float q2 = rdlane_f(pw, j + 2), q3 = rdlane_f(pw, j + 3);
            float q4 = rdlane_f(pw, j + 4), q5 = rdlane_f(pw, j + 5);
            float q6 = rdlane_f(pw, j + 6), q7 = rdlane_f(pw, j + 7);
            hacc = fmaf(e0, lo16(u0), hacc); mf = fmaxf(mf, q0 * hi16(u0));
            hacc = fmaf(e1, lo16(u1), hacc); mf = fmaxf(mf, q1 * hi16(u1));
            hacc = fmaf(e2, lo16(u2), hacc); mf = fmaxf(mf, q2 * hi16(u2));
            hacc = fmaf(e3, lo16(u3), hacc); mf = fmaxf(mf, q3 * hi16(u3));
            hacc = fmaf(e4, lo16(u4), hacc); mf = fmaxf(mf, q4 * hi16(u4));
            hacc = fmaf(e5, lo16(u5), hacc); mf = fmaxf(mf, q5 * hi16(u5));
            hacc = fmaf(e6, lo16(u6), hacc); mf = fmaxf(mf, q6 * hi16(u6));
            hacc = fmaf(e7, lo16(u7), hacc); mf = fmaxf(mf, q7 * hi16(u7));
        }
        for (; j < cnt; ++j) {
            int   s0 = rdlane_i(s_e, j);
            unsigned int u0 = pzgp[(size_t)s0 * 64 + lane];
            float e0 = rdlane_f(ex, j);
            float q0 = rdlane_f(pw, j);
            hacc = fmaf(e0, lo16(u0), hacc); mf = fmaxf(mf, q0 * hi16(u0));
        }
    }

    float mfv = (dg > 0) ? mf : 0.f;
    float gdot = gm[lane] * mfv;
    #pragma unroll
    for (int o = 32; o > 0; o >>= 1) gdot += __shfl_xor(gdot, o);
    float mean = msum / fmaxf((float)dg, 1.f);
    float x = vg0n + gdot + mean;
    float gv = 1.f / (1.f + __expf(-x));

    float pz = proj_z[(size_t)n * 64 + lane];
    out[(size_t)n * 64 + lane] = pz + ((dg > 0) ? gv * hacc / den : 0.f);
}

// ---------------------------------------------------------------------------
extern "C" void kernel_launch(void* const* d_in, const int* in_sizes, int n_in,
                              void* d_out, int out_size, void* d_ws, size_t ws_size,
                              hipStream_t stream)
{
    const float* v      = (const float*)d_in[0];
    const float* proj_z = (const float*)d_in[1];
    const float* pre_w  = (const float*)d_in[2];
    const float* Wa_w   = (const float*)d_in[3];
    const float* attl_w = (const float*)d_in[4];
    const float* attr_w = (const float*)d_in[5];
    const float* Wg_w   = (const float*)d_in[6];
    const float* gl_w   = (const float*)d_in[7];
    const float* gm_w   = (const float*)d_in[8];
    const float* gr_w   = (const float*)d_in[9];
    const int*   src    = (const int*)d_in[10];
    const int*   dst    = (const int*)d_in[11];

    const int N = in_sizes[0] / 64;
    const int E = in_sizes[10];
    float* out = (float*)d_out;

    const int NB    = (E + 4095) / 4096;       // edge chunks (256)
    const int NBUCK = (N + 255) / 256;         // buckets (256)
    const int M     = NBUCK * NB;              // 65536
    const int NBLK  = (M + 255) / 256;         // 256 scan blocks

    // workspace carve-up (~30 MB); 8B alignment kept.
    char* ws = (char*)d_ws;
    unsigned int* pzgp = (unsigned int*)ws; ws += (size_t)N * 64 * 4;
    int2*   buf1  = (int2*)ws;   ws += (size_t)E * 8;
    unsigned int* edata = (unsigned int*)ws; ws += (size_t)E * 4;
    float2* slvr  = (float2*)ws; ws += (size_t)N * 8;
    float2* srvg  = (float2*)ws; ws += (size_t)N * 8;
    int*    offs  = (int*)ws;    ws += (size_t)N * 4;
    int*    deg   = (int*)ws;    ws += (size_t)N * 4;
    int*    pos   = (int*)ws;    ws += (size_t)M * 4;
    int*    bsum  = (int*)ws;    ws += (size_t)NBLK * 4;
    float*  alar  = (float*)ws;  ws += 128 * 4;

    prep_al<<<1, 256, 0, stream>>>(Wa_w, attl_w, attr_w, alar);

    int nTiles = (N + 63) / 64;
    int npb = nTiles < 1024 ? nTiles : 1024;
    node_pre<<<npb, 512, 0, stream>>>(v, proj_z, alar, Wg_w, gl_w, gr_w,
                                      slvr, srvg, pzgp, N);

    k_hist  <<<NB, 256, 0, stream>>>(dst, pos, E, NB, NBUCK);
    ps_block<<<NBLK, 256, 0, stream>>>(pos, bsum, M);
    ps_top  <<<1, 256, 0, stream>>>(bsum, NBLK);
    k_scat1 <<<NB, 256, 0, stream>>>(dst, src, pre_w, pos, bsum, buf1,
                                     E, NB, NBUCK);
    k_scat2 <<<NBUCK, 256, 0, stream>>>(buf1, pos, bsum, edata, deg, offs,
                                        E, NB, NBUCK, N);

    main_k<<<(N + 1) / 2, 128, 0, stream>>>(proj_z, slvr, srvg,
                                            pzgp, gm_w, deg, offs, edata, out, N);
}

// Round 20
// 122.813 us; speedup vs baseline: 1.0580x; 1.0580x over previous
//
#include <hip/hip_runtime.h>
#include <hip/hip_bf16.h>
#include <math.h>

#define NEG_SLOPE 0.01f

// Shapes tuned for: N=65536 nodes, E=1048576 edges, dim 64.
// Assumptions: N <= 2^16 (src packs into 16 bits of the edge word).
// r20 = r18 byte-for-byte (best measured: 121.7us). r19's prep_al +
// 512-thread node_pre regressed (4th failed node_pre rewrite); reverted.
//
// Pipeline: node_pre (per-node scalars + packed bf16 pz|gp table) ->
// bucket-sort CSR build (hist, hierarchical scan, 2-level scatter; LDS
// atomics only) -> main_k (one wave per dst node, no-max softmax, one
// 4B gather per edge per lane).
// main_k sits at its structural fetch floor: FETCH 130MB = 8 XCDs x
// 16.3MB pzgp table (uniform-random src, non-coherent L2s) at ~2.4TB/s.

__device__ __forceinline__ unsigned int pack2bf16(float pz, float g)
{
    __hip_bfloat16 a = __float2bfloat16(pz);   // RNE
    __hip_bfloat16 b = __float2bfloat16(g);
    unsigned short ua = *(unsigned short*)&a;
    unsigned short ub = *(unsigned short*)&b;
    return ((unsigned int)ub << 16) | ua;
}

__device__ __forceinline__ unsigned short f2bf(float x)
{
    __hip_bfloat16 b = __float2bfloat16(x);
    return *(unsigned short*)&b;
}

__device__ __forceinline__ int rdlane_i(int x, int l)
{
    return __builtin_amdgcn_readlane(x, l);
}
__device__ __forceinline__ float rdlane_f(float x, int l)
{
    return __int_as_float(__builtin_amdgcn_readlane(__float_as_int(x), l));
}
__device__ __forceinline__ float lo16(unsigned int u) { return __uint_as_float(u << 16); }
__device__ __forceinline__ float hi16(unsigned int u) { return __uint_as_float(u & 0xffff0000u); }

// ---------------------------------------------------------------------------
// node_pre (r9 form -- rewrites in r10/r12/r16/r19 all regressed).
//   slvr[n] = (v[n].al, v[n].gr)   srvg[n] = (v[n].ar, v[n].gl)
//   pzgp[n][d] = pack(bf16(proj_z[n][d]), bf16((Wg @ v[n])[d]))
// ---------------------------------------------------------------------------
__global__ __launch_bounds__(256) void node_pre(
    const float* __restrict__ v, const float* __restrict__ proj_z,
    const float* __restrict__ Wa,
    const float* __restrict__ attl, const float* __restrict__ attr,
    const float* __restrict__ Wg, const float* __restrict__ gl,
    const float* __restrict__ gr,
    float2* __restrict__ slvr, float2* __restrict__ srvg,
    unsigned int* __restrict__ pzgp, int N)
{
    __shared__ float vtile[64 * 68];     // stride 68: conflict-free
    __shared__ float avecs[4][64];       // 0=al(=attl@Wa), 1=ar, 2=gl, 3=gr
    __shared__ float pal[4][64], par[4][64];

    int t = threadIdx.x;
    int lane = t & 63;
    int w = t >> 6;

    // cooperative preamble: wave w covers k in [w*16, w*16+16)
    {
        float ald = 0.f, ard = 0.f;
        #pragma unroll
        for (int kk = 0; kk < 16; ++kk) {
            int k = w * 16 + kk;
            float wa = Wa[k * 64 + lane];
            ald = fmaf(attl[k], wa, ald);
            ard = fmaf(attr[k], wa, ard);
        }
        pal[w][lane] = ald;
        par[w][lane] = ard;
    }
    __syncthreads();
    if (w == 0) {
        avecs[0][lane] = pal[0][lane] + pal[1][lane] + pal[2][lane] + pal[3][lane];
        avecs[1][lane] = par[0][lane] + par[1][lane] + par[2][lane] + par[3][lane];
        avecs[2][lane] = gl[lane];
        avecs[3][lane] = gr[lane];
    }

    for (int tile = blockIdx.x; (size_t)tile * 64 < (size_t)N; tile += gridDim.x) {
        int base = tile * 64;
        __syncthreads();                   // protects vtile AND first-use of avecs

        float p1 = 0.f, p2 = 0.f, p3 = 0.f, p4 = 0.f;
        #pragma unroll
        for (int i = 0; i < 4; ++i) {
            int el = t * 16 + i * 4;
            size_t gidx = (size_t)base * 64 + el;
            int c = (t & 3) * 16 + i * 4;
            if (gidx + 3 < (size_t)N * 64) {
                float4 q = *(const float4*)(v + gidx);
                int r = el >> 6;
                *(float4*)&vtile[r * 68 + c] = q;
                float4 a0 = *(const float4*)&avecs[0][c];
                float4 a1 = *(const float4*)&avecs[1][c];
                float4 a2 = *(const float4*)&avecs[2][c];
                float4 a3 = *(const float4*)&avecs[3][c];
                p1 = fmaf(a0.x, q.x, fmaf(a0.y, q.y, fmaf(a0.z, q.z, fmaf(a0.w, q.w, p1))));
                p2 = fmaf(a1.x, q.x, fmaf(a1.y, q.y, fmaf(a1.z, q.z, fmaf(a1.w, q.w, p2))));
                p3 = fmaf(a2.x, q.x, fmaf(a2.y, q.y, fmaf(a2.z, q.z, fmaf(a2.w, q.w, p3))));
                p4 = fmaf(a3.x, q.x, fmaf(a3.y, q.y, fmaf(a3.z, q.z, fmaf(a3.w, q.w, p4))));
            }
        }
        __syncthreads();

        p1 += __shfl_xor(p1, 1); p1 += __shfl_xor(p1, 2);
        p2 += __shfl_xor(p2, 1); p2 += __shfl_xor(p2, 2);
        p3 += __shfl_xor(p3, 1); p3 += __shfl_xor(p3, 2);
        p4 += __shfl_xor(p4, 1); p4 += __shfl_xor(p4, 2);
        if ((t & 3) == 0) {
            int node = base + (t >> 2);
            if (node < N) {
                slvr[node] = make_float2(p1, p4);   // (sl, vr)
                srvg[node] = make_float2(p2, p3);   // (sr, vg0)
            }
        }

        // gp = vtile @ Wg^T, K-chunked (16 Wg floats + 16 accs live)
        float accs[16];
        #pragma unroll
        for (int n = 0; n < 16; ++n) accs[n] = 0.f;

        #pragma unroll 1
        for (int kc = 0; kc < 4; ++kc) {
            const float* wrow = Wg + lane * 64 + kc * 16;
            float4 w0 = *(const float4*)(wrow + 0);
            float4 w1 = *(const float4*)(wrow + 4);
            float4 w2 = *(const float4*)(wrow + 8);
            float4 w3 = *(const float4*)(wrow + 12);
            #pragma unroll
            for (int n = 0; n < 16; ++n) {
                const float* vp = &vtile[(w * 16 + n) * 68 + kc * 16];
                float4 q0 = *(const float4*)(vp + 0);
                float4 q1 = *(const float4*)(vp + 4);
                float4 q2 = *(const float4*)(vp + 8);
                float4 q3 = *(const float4*)(vp + 12);
                float a = accs[n];
                a = fmaf(w0.x, q0.x, a); a = fmaf(w0.y, q0.y, a);
                a = fmaf(w0.z, q0.z, a); a = fmaf(w0.w, q0.w, a);
                a = fmaf(w1.x, q1.x, a); a = fmaf(w1.y, q1.y, a);
                a = fmaf(w1.z, q1.z, a); a = fmaf(w1.w, q1.w, a);
                a = fmaf(w2.x, q2.x, a); a = fmaf(w2.y, q2.y, a);
                a = fmaf(w2.z, q2.z, a); a = fmaf(w2.w, q2.w, a);
                a = fmaf(w3.x, q3.x, a); a = fmaf(w3.y, q3.y, a);
                a = fmaf(w3.z, q3.z, a); a = fmaf(w3.w, q3.w, a);
                accs[n] = a;
            }
        }

        #pragma unroll
        for (int n = 0; n < 16; ++n) {
            int node = base + w * 16 + n;
            if (node < N) {
                float pz = proj_z[(size_t)node * 64 + lane];
                pzgp[(size_t)node * 64 + lane] = pack2bf16(pz, accs[n]);
            }
        }
    }
}

// ---------------------------------------------------------------------------
// Bucket-sort CSR build (LDS atomics only; no global atomics, no memsets).
// ---------------------------------------------------------------------------
__global__ __launch_bounds__(256) void k_hist(const int* __restrict__ dst,
                                              int* __restrict__ cnt,
                                              int E, int NB, int NBUCK)
{
    __shared__ int h[256];
    int t = threadIdx.x, b = blockIdx.x;
    h[t] = 0;
    __syncthreads();
    int base = b * 4096;
    for (int i = t; i < 4096; i += 256) {
        int e = base + i;
        if (e < E) atomicAdd(&h[dst[e] >> 8], 1);
    }
    __syncthreads();
    for (int q = t; q < NBUCK; q += 256) cnt[q * NB + b] = h[q];
}

__global__ __launch_bounds__(256) void ps_block(int* __restrict__ data,
                                                int* __restrict__ bsum, int M)
{
    __shared__ int tmp[256];
    int t = threadIdx.x;
    int i = blockIdx.x * 256 + t;
    int val = (i < M) ? data[i] : 0;
    tmp[t] = val;
    __syncthreads();
    #pragma unroll
    for (int o = 1; o < 256; o <<= 1) {
        int x = (t >= o) ? tmp[t - o] : 0;
        __syncthreads();
        tmp[t] += x;
        __syncthreads();
    }
    if (i < M) data[i] = tmp[t] - val;
    if (t == 255) bsum[blockIdx.x] = tmp[255];
}

__global__ __launch_bounds__(256) void ps_top(int* __restrict__ bsum, int NBLK)
{
    __shared__ int tmp[256];
    int t = threadIdx.x;
    int val = (t < NBLK) ? bsum[t] : 0;
    tmp[t] = val;
    __syncthreads();
    #pragma unroll
    for (int o = 1; o < 256; o <<= 1) {
        int x = (t >= o) ? tmp[t - o] : 0;
        __syncthreads();
        tmp[t] += x;
        __syncthreads();
    }
    if (t < NBLK) bsum[t] = tmp[t] - val;
}

__global__ __launch_bounds__(256) void k_scat1(
    const int* __restrict__ dst, const int* __restrict__ src,
    const float* __restrict__ pre_w, const int* __restrict__ pos,
    const int* __restrict__ bsum,
    int2* __restrict__ buf1, int E, int NB, int NBUCK)
{
    __shared__ int cur[256];
    int t = threadIdx.x, b = blockIdx.x;
    for (int q = t; q < NBUCK; q += 256) {
        int idx = q * NB + b;
        cur[q] = pos[idx] + bsum[idx >> 8];
    }
    __syncthreads();
    int base = b * 4096;
    for (int i = t; i < 4096; i += 256) {
        int e = base + i;
        if (e < E) {
            int d = dst[e];
            int p = atomicAdd(&cur[d >> 8], 1);    // LDS atomic
            int2 pk;
            pk.x = ((d & 255) << 24) | src[e];
            pk.y = __float_as_int(pre_w[e]);
            buf1[p] = pk;
        }
    }
}

// scat2 emits 4-byte packed edges: src:16 | pw(bf16):16
__global__ __launch_bounds__(256) void k_scat2(
    const int2* __restrict__ buf1, const int* __restrict__ pos,
    const int* __restrict__ bsum,
    unsigned int* __restrict__ edata, int* __restrict__ deg,
    int* __restrict__ offs,
    int E, int NB, int NBUCK, int N)
{
    __shared__ int h[256], bs[256];
    int B = blockIdx.x, t = threadIdx.x;
    int i0 = B * NB;
    int lo = pos[i0] + bsum[i0 >> 8];
    int hi = E;
    if (B + 1 < NBUCK) {
        int i1 = (B + 1) * NB;
        hi = pos[i1] + bsum[i1 >> 8];
    }
    int cB = hi - lo;

    h[t] = 0;
    __syncthreads();
    for (int i = t; i < cB; i += 256)
        atomicAdd(&h[(unsigned)buf1[lo + i].x >> 24], 1);
    __syncthreads();

    int val = h[t];
    bs[t] = val;
    __syncthreads();
    #pragma unroll
    for (int o = 1; o < 256; o <<= 1) {
        int x = (t >= o) ? bs[t - o] : 0;
        __syncthreads();
        bs[t] += x;
        __syncthreads();
    }
    int mybs = bs[t] - val;

    int node = (B << 8) + t;
    if (node < N) { deg[node] = val; offs[node] = lo + mybs; }

    h[t] = mybs;
    __syncthreads();
    for (int i = t; i < cB; i += 256) {
        int2 pk = buf1[lo + i];
        int bin = (unsigned)pk.x >> 24;
        int p = atomicAdd(&h[bin], 1);    // LDS atomic
        unsigned int srcw = (unsigned)pk.x & 0x0000FFFFu;           // src (16b)
        unsigned int pwb  = (unsigned int)f2bf(__int_as_float(pk.y));
        edata[lo + p] = srcw | (pwb << 16);
    }
}

// ---------------------------------------------------------------------------
// main_k: one wave per dst node, lane = output dim. 2-wave blocks, 8-wide
// gather, no-max softmax, 4-byte packed edges.
// ---------------------------------------------------------------------------
__global__ __launch_bounds__(128) void main_k(
    const float* __restrict__ proj_z,
    const float2* __restrict__ slvr, const float2* __restrict__ srvg,
    const unsigned int* __restrict__ pzgp, const float* __restrict__ gm,
    const int* __restrict__ deg, const int* __restrict__ offs,
    const unsigned int* __restrict__ edata,
    float* __restrict__ out, int N)
{
    int n = (blockIdx.x * 128 + threadIdx.x) >> 6;
    int lane = threadIdx.x & 63;
    if (n >= N) return;

    int dg = deg[n];
    int st = offs[n];
    float2 sv = srvg[n];
    float srn = sv.x, vg0n = sv.y;

    float den = 0.f, hacc = 0.f, mf = -INFINITY, msum = 0.f;

    for (int base = 0; base < dg; base += 64) {
        int cnt = min(64, dg - base);

        int s_e = 0; float pw = 0.f, ex = 0.f, vre = 0.f;
        if (lane < cnt) {
            unsigned int ed = edata[st + base + lane];
            s_e = (int)(ed & 0xFFFFu);
            pw  = __uint_as_float(ed & 0xFFFF0000u);   // bf16 -> f32 (hi bits)
            float2 f = slvr[s_e];
            float a = fmaf(pw, f.x, srn);
            float lr = (a >= 0.f) ? a : NEG_SLOPE * a;
            ex = __expf(lr);                 // no max subtraction (bounded logits)
            vre = f.y;
        }

        // lane-parallel reductions for den and msum
        float rs1 = ex, rs2 = pw * vre;
        #pragma unroll
        for (int o = 32; o > 0; o >>= 1) {
            rs1 += __shfl_xor(rs1, o);
            rs2 += __shfl_xor(rs2, o);
        }
        den += rs1; msum += rs2;

        // per-dim gathers: readlane broadcasts + 8 loads in flight
        int j = 0;
        for (; j + 7 < cnt; j += 8) {
            int s0 = rdlane_i(s_e, j + 0), s1 = rdlane_i(s_e, j + 1);
            int s2 = rdlane_i(s_e, j + 2), s3 = rdlane_i(s_e, j + 3);
            int s4 = rdlane_i(s_e, j + 4), s5 = rdlane_i(s_e, j + 5);
            int s6 = rdlane_i(s_e, j + 6), s7 = rdlane_i(s_e, j + 7);
            unsigned int u0 = pzgp[(size_t)s0 * 64 + lane];
            unsigned int u1 = pzgp[(size_t)s1 * 64 + lane];
            unsigned int u2 = pzgp[(size_t)s2 * 64 + lane];
            unsigned int u3 = pzgp[(size_t)s3 * 64 + lane];
            unsigned int u4 = pzgp[(size_t)s4 * 64 + lane];
            unsigned int u5 = pzgp[(size_t)s5 * 64 + lane];
            unsigned int u6 = pzgp[(size_t)s6 * 64 + lane];
            unsigned int u7 = pzgp[(size_t)s7 * 64 + lane];
            float e0 = rdlane_f(ex, j + 0), e1 = rdlane_f(ex, j + 1);
            float e2 = rdlane_f(ex, j + 2), e3 = rdlane_f(ex, j + 3);
            float e4 = rdlane_f(ex, j + 4), e5 = rdlane_f(ex, j + 5);
            float e6 = rdlane_f(ex, j + 6), e7 = rdlane_f(ex, j + 7);
            float q0 = rdlane_f(pw, j + 0), q1 = rdlane_f(pw, j + 1);
            float q2 = rdlane_f(pw, j + 2), q3 = rdlane_f(pw, j + 3);
            float q4 = rdlane_f(pw, j + 4), q5 = rdlane_f(pw, j + 5);
            float q6 = rdlane_f(pw, j + 6), q7 = rdlane_f(pw, j + 7);
            hacc = fmaf(e0, lo16(u0), hacc); mf = fmaxf(mf, q0 * hi16(u0));
            hacc = fmaf(e1, lo16(u1), hacc); mf = fmaxf(mf, q1 * hi16(u1));
            hacc = fmaf(e2, lo16(u2), hacc); mf = fmaxf(mf, q2 * hi16(u2));
            hacc = fmaf(e3, lo16(u3), hacc); mf = fmaxf(mf, q3 * hi16(u3));
            hacc = fmaf(e4, lo16(u4), hacc); mf = fmaxf(mf, q4 * hi16(u4));
            hacc = fmaf(e5, lo16(u5), hacc); mf = fmaxf(mf, q5 * hi16(u5));
            hacc = fmaf(e6, lo16(u6), hacc); mf = fmaxf(mf, q6 * hi16(u6));
            hacc = fmaf(e7, lo16(u7), hacc); mf = fmaxf(mf, q7 * hi16(u7));
        }
        for (; j < cnt; ++j) {
            int   s0 = rdlane_i(s_e, j);
            unsigned int u0 = pzgp[(size_t)s0 * 64 + lane];
            float e0 = rdlane_f(ex, j);
            float q0 = rdlane_f(pw, j);
            hacc = fmaf(e0, lo16(u0), hacc); mf = fmaxf(mf, q0 * hi16(u0));
        }
    }

    float mfv = (dg > 0) ? mf : 0.f;
    float gdot = gm[lane] * mfv;
    #pragma unroll
    for (int o = 32; o > 0; o >>= 1) gdot += __shfl_xor(gdot, o);
    float mean = msum / fmaxf((float)dg, 1.f);
    float x = vg0n + gdot + mean;
    float gv = 1.f / (1.f + __expf(-x));

    float pz = proj_z[(size_t)n * 64 + lane];
    out[(size_t)n * 64 + lane] = pz + ((dg > 0) ? gv * hacc / den : 0.f);
}

// ---------------------------------------------------------------------------
extern "C" void kernel_launch(void* const* d_in, const int* in_sizes, int n_in,
                              void* d_out, int out_size, void* d_ws, size_t ws_size,
                              hipStream_t stream)
{
    const float* v      = (const float*)d_in[0];
    const float* proj_z = (const float*)d_in[1];
    const float* pre_w  = (const float*)d_in[2];
    const float* Wa_w   = (const float*)d_in[3];
    const float* attl_w = (const float*)d_in[4];
    const float* attr_w = (const float*)d_in[5];
    const float* Wg_w   = (const float*)d_in[6];
    const float* gl_w   = (const float*)d_in[7];
    const float* gm_w   = (const float*)d_in[8];
    const float* gr_w   = (const float*)d_in[9];
    const int*   src    = (const int*)d_in[10];
    const int*   dst    = (const int*)d_in[11];

    const int N = in_sizes[0] / 64;
    const int E = in_sizes[10];
    float* out = (float*)d_out;

    const int NB    = (E + 4095) / 4096;       // edge chunks (256)
    const int NBUCK = (N + 255) / 256;         // buckets (256)
    const int M     = NBUCK * NB;              // 65536
    const int NBLK  = (M + 255) / 256;         // 256 scan blocks

    // workspace carve-up (~30 MB); 8B alignment kept.
    char* ws = (char*)d_ws;
    unsigned int* pzgp = (unsigned int*)ws; ws += (size_t)N * 64 * 4;
    int2*   buf1  = (int2*)ws;   ws += (size_t)E * 8;
    unsigned int* edata = (unsigned int*)ws; ws += (size_t)E * 4;
    float2* slvr  = (float2*)ws; ws += (size_t)N * 8;
    float2* srvg  = (float2*)ws; ws += (size_t)N * 8;
    int*    offs  = (int*)ws;    ws += (size_t)N * 4;
    int*    deg   = (int*)ws;    ws += (size_t)N * 4;
    int*    pos   = (int*)ws;    ws += (size_t)M * 4;
    int*    bsum  = (int*)ws;    ws += (size_t)NBLK * 4;

    int nTiles = (N + 63) / 64;
    int npb = nTiles < 1024 ? nTiles : 1024;
    node_pre<<<npb, 256, 0, stream>>>(v, proj_z, Wa_w, attl_w, attr_w, Wg_w,
                                      gl_w, gr_w, slvr, srvg, pzgp, N);

    k_hist  <<<NB, 256, 0, stream>>>(dst, pos, E, NB, NBUCK);
    ps_block<<<NBLK, 256, 0, stream>>>(pos, bsum, M);
    ps_top  <<<1, 256, 0, stream>>>(bsum, NBLK);
    k_scat1 <<<NB, 256, 0, stream>>>(dst, src, pre_w, pos, bsum, buf1,
                                     E, NB, NBUCK);
    k_scat2 <<<NBUCK, 256, 0, stream>>>(buf1, pos, bsum, edata, deg, offs,
                                        E, NB, NBUCK, N);

    main_k<<<(N + 1) / 2, 128, 0, stream>>>(proj_z, slvr, srvg,
                                            pzgp, gm_w, deg, offs, edata, out, N);
}